// Round 13
// baseline (761.243 us; speedup 1.0000x reference)
//
#include <hip/hip_runtime.h>

typedef __attribute__((ext_vector_type(8))) short short8;
typedef __attribute__((ext_vector_type(4))) float f32x4;

__device__ inline ushort f2bf(float f) {
  union { float f; unsigned u; } v; v.f = f;
  return (ushort)((v.u + 0x7fffu + ((v.u >> 16) & 1u)) >> 16);
}

// tanh via v_exp_f32 + v_rcp_f32: ~8 VALU ops, rel err ~1e-6 (<< bf16 rounding)
__device__ inline float fast_tanh(float x) {
  float ax = __builtin_fabsf(x);
  float u = __builtin_amdgcn_exp2f(-2.8853900817779268f * ax);   // e^{-2|x|}
  float r = (1.0f - u) * __builtin_amdgcn_rcpf(1.0f + u);
  return __builtin_copysignf(r, x);
}

// ---------------- weight prep: pack into per-MFMA-fragment order ----------------
// Wtp [64][8][64][8]: n = nt*16+(lane&15), k = ks*32+(lane>>4)*8+m, pi_w[k*1024+n]
// iiWtp2 [8][8][64][8] (K=256 duplicated): d = dt*16+(lane&15),
//   c' = ks*32+(lane>>4)*8+m (ks<8), weight = ii_w[(c'&127)*128+d]
// ppW1p/ppW2p [8][4][64][8]: c = ct*16+(lane&15), k = ks*32+(lane>>4)*8+m, w[k*128+c]
__global__ __launch_bounds__(256)
void prep_weights(const float* __restrict__ pi_w, const float* __restrict__ ii_w,
                  const float* __restrict__ pp_w1, const float* __restrict__ pp_w2,
                  ushort* __restrict__ Wtp, ushort* __restrict__ iiWtp2,
                  ushort* __restrict__ ppW1p, ushort* __restrict__ ppW2p)
{
  int tid = blockIdx.x * 256 + threadIdx.x;
  if (tid < 262144) {
    int m = tid & 7, lane = (tid >> 3) & 63, ks = (tid >> 9) & 7, nt = tid >> 12;
    int k = ks * 32 + (lane >> 4) * 8 + m;
    int n = nt * 16 + (lane & 15);
    Wtp[tid] = f2bf(pi_w[k * 1024 + n]);
  } else if (tid < 262144 + 32768) {
    int t = tid - 262144;
    int m = t & 7, lane = (t >> 3) & 63, ks = (t >> 9) & 7, dt = t >> 12;
    int cp = ks * 32 + (lane >> 4) * 8 + m;
    int d = dt * 16 + (lane & 15);
    iiWtp2[t] = f2bf(ii_w[(cp & 127) * 128 + d]);
  } else {
    int t = tid - 262144 - 32768;   // [0, 32768)
    int m = t & 7, lane = (t >> 3) & 63, ks = (t >> 9) & 3, ct = (t >> 11) & 7;
    int k = ks * 32 + (lane >> 4) * 8 + m;
    int c = ct * 16 + (lane & 15);
    if (t < 16384) ppW1p[t]         = f2bf(pp_w1[k * 128 + c]);
    else           ppW2p[t - 16384] = f2bf(pp_w2[k * 128 + c]);
  }
}

// ---------------- pp via MFMA: h = tanh(tanh(p1@W1+b1)@W2+b2) -> bf16 ----------------
template <bool FULL>
__global__ __launch_bounds__(256)
void pp_mfma_kernel(const float* __restrict__ p1,
                    const ushort* __restrict__ W1p, const float* __restrict__ b1,
                    const ushort* __restrict__ W2p, const float* __restrict__ b2,
                    ushort* __restrict__ hbf, int N, int blk0)
{
  __shared__ ushort Xs2[64 * 128];   // [n][k] bf16, rows 256B, byte ^= (n&7)<<4
  const int tid = threadIdx.x;
  const int wave = tid >> 6;
  const int lane = tid & 63;
  const int lane16 = lane & 15;
  const int lgrp = lane >> 4;
  const int n0 = (blk0 + (int)blockIdx.x) * 64;

  // --- stage p1 (f32 -> bf16), coalesced ---
  #pragma unroll
  for (int p = 0; p < 8; ++p) {
    int fi = p * 256 + tid;          // float4 index
    int n = fi >> 5;
    int k0 = (fi & 31) * 4;
    int gn = n0 + n;
    if (!FULL) gn = gn < N ? gn : N - 1;
    float4 v = *(const float4*)(p1 + (size_t)gn * 128 + k0);
    ushort4 u;
    u.x = f2bf(v.x); u.y = f2bf(v.y); u.z = f2bf(v.z); u.w = f2bf(v.w);
    *(ushort4*)((char*)Xs2 + n * 256 + ((k0 * 2) ^ ((n & 7) << 4))) = u;
  }
  __syncthreads();

  const ushort* Wp = W1p;
  const float* bp = b1;
  #pragma unroll
  for (int layer = 0; layer < 2; ++layer) {
    short8 xf2[4][4];
    #pragma unroll
    for (int et = 0; et < 4; ++et) {
      int n = et * 16 + lane16;
      #pragma unroll
      for (int ks = 0; ks < 4; ++ks)
        xf2[et][ks] = *(const short8*)((const char*)Xs2 + n * 256 + ((ks * 64 + lgrp * 16) ^ ((n & 7) << 4)));
    }
    ushort4 uo[2][4];
    #pragma unroll
    for (int ct = 0; ct < 2; ++ct) {
      const int ctg = wave * 2 + ct;
      const float4 bb = *(const float4*)(bp + ctg * 16 + lgrp * 4);
      f32x4 acc[4];
      #pragma unroll
      for (int et = 0; et < 4; ++et) acc[et] = (f32x4){bb.x, bb.y, bb.z, bb.w};
      __builtin_amdgcn_s_setprio(1);
      #pragma unroll
      for (int ks = 0; ks < 4; ++ks) {
        short8 a = *(const short8*)(Wp + ((size_t)(ctg * 4 + ks) * 64 + lane) * 8);
        #pragma unroll
        for (int et = 0; et < 4; ++et)
          acc[et] = __builtin_amdgcn_mfma_f32_16x16x32_bf16(a, xf2[et][ks], acc[et], 0, 0, 0);
      }
      __builtin_amdgcn_s_setprio(0);
      #pragma unroll
      for (int et = 0; et < 4; ++et) {
        uo[ct][et].x = f2bf(fast_tanh(acc[et][0]));
        uo[ct][et].y = f2bf(fast_tanh(acc[et][1]));
        uo[ct][et].z = f2bf(fast_tanh(acc[et][2]));
        uo[ct][et].w = f2bf(fast_tanh(acc[et][3]));
      }
    }
    __syncthreads();   // all waves done reading Xs2
    #pragma unroll
    for (int ct = 0; ct < 2; ++ct) {
      int c0 = (wave * 2 + ct) * 16 + lgrp * 4;
      #pragma unroll
      for (int et = 0; et < 4; ++et) {
        int n = et * 16 + lane16;
        *(ushort4*)((char*)Xs2 + n * 256 + ((c0 * 2) ^ ((n & 7) << 4))) = uo[ct][et];
      }
    }
    __syncthreads();
    Wp = W2p; bp = b2;
  }

  // --- coalesced copy-out (16B chunks) ---
  #pragma unroll
  for (int p = 0; p < 4; ++p) {
    int si = p * 256 + tid;
    int n = si >> 4;
    int c0 = (si & 15) * 8;
    int4 v = *(const int4*)((const char*)Xs2 + n * 256 + ((c0 * 2) ^ ((n & 7) << 4)));
    if (FULL || n0 + n < N)
      *(int4*)(hbf + (size_t)(n0 + n) * 128 + c0) = v;
  }
}

// ---------------- fused edge kernel (swapped-operand MFMA, 48 edges/block) ----------------
// pi epilogue is shuffle-free: both b-half partials stored to Ys[e][c'],
// c' = cg + (lgrp&1)*128; ii GEMM runs K=256 against duplicated iiWtp2.
template <bool FULL>
__global__ __launch_bounds__(256, 3)
void edge_kernel(const ushort* __restrict__ hbf,
                 const int* __restrict__ idx_i, const int* __restrict__ idx_j,
                 const float* __restrict__ basis,
                 const ushort* __restrict__ Wtp,    // packed [64][8][64][8]
                 const float* __restrict__ pi_b,    // [1024]
                 const ushort* __restrict__ iiWtp2, // packed [8][8][64][8], K=256 dup
                 const float* __restrict__ ii_b,    // [128]
                 float* __restrict__ out, int E, int blk0)
{
  __shared__ ushort Xs[48 * 256];               // 24 KB; reused as f32 transpose buf
  __shared__ ushort Ys[48 * 256];               // 24 KB, rows of 512B, byte ^= (e&7)<<4
  __shared__ alignas(16) float basis_s[48 * 8];
  __shared__ int idxj_s[48];

  const int tid = threadIdx.x;
  const int wave = tid >> 6;
  const int lane = tid & 63;
  const int lane16 = lane & 15;
  const int lgrp = lane >> 4;
  const size_t e0 = (size_t)(blk0 + (int)blockIdx.x) * 48;
  const size_t elim = (size_t)E - 1;

  // --- stage X (gather 96 rows of 256B, coalesced 16B/lane) ---
  #pragma unroll
  for (int pass = 0; pass < 6; ++pass) {
    int r = pass * 16 + (tid >> 4);
    int l16 = tid & 15;
    int e = r >> 1;
    size_t eg = e0 + e;
    if (!FULL) { if (eg > elim) eg = elim; }
    int node = (r & 1) ? idx_j[eg] : idx_i[eg];
    int4 v = *(const int4*)(hbf + (size_t)node * 128 + l16 * 8);
    int kb = ((r & 1) * 128 + l16 * 8) * 2;
    *(int4*)((char*)Xs + e * 512 + (kb ^ ((e & 7) << 4))) = v;
  }
  if (FULL) {
    basis_s[tid] = basis[e0 * 8 + tid];
    if (tid < 128) basis_s[256 + tid] = basis[e0 * 8 + 256 + tid];
    if (tid < 48) idxj_s[tid] = idx_j[e0 + tid];
  } else {
    size_t blim = (size_t)E * 8 - 1;
    size_t i1 = e0 * 8 + tid;        if (i1 > blim) i1 = blim;
    basis_s[tid] = basis[i1];
    if (tid < 128) {
      size_t i2 = e0 * 8 + 256 + tid; if (i2 > blim) i2 = blim;
      basis_s[256 + tid] = basis[i2];
    }
    if (tid < 48) {
      size_t eg = e0 + tid; if (eg > elim) eg = elim;
      idxj_s[tid] = idx_j[eg];
    }
  }
  __syncthreads();

  // --- hoist X fragments to registers and PIN them (96 regs) ---
  short8 xf[3][8];
  #pragma unroll
  for (int et = 0; et < 3; ++et) {
    int e = et * 16 + lane16;
    #pragma unroll
    for (int ks = 0; ks < 8; ++ks) {
      xf[et][ks] = *(const short8*)((const char*)Xs + e * 512 + ((ks * 64 + lgrp * 16) ^ ((e & 7) << 4)));
      asm volatile("" : "+v"(xf[et][ks]));
    }
  }
  float4 bas[3];
  #pragma unroll
  for (int et = 0; et < 3; ++et) {
    int e = et * 16 + lane16;
    bas[et] = *(const float4*)((const char*)basis_s + e * 32 + (lgrp & 1) * 16);
  }

  // --- pi GEMM + basis fold, rotate-prefetched a-frag stream ---
  short8 af[8];
  #pragma unroll
  for (int ks = 0; ks < 8; ++ks)
    af[ks] = *(const short8*)(Wtp + ((size_t)((wave * 16) * 8 + ks) * 64 + lane) * 8);

  #pragma unroll
  for (int ct = 0; ct < 16; ++ct) {
    const int ntg = wave * 16 + ct;
    const float4 pib = *(const float4*)(pi_b + ntg * 16 + lgrp * 4);
    f32x4 acc[3];
    #pragma unroll
    for (int et = 0; et < 3; ++et)
      acc[et] = (f32x4){pib.x, pib.y, pib.z, pib.w};
    __builtin_amdgcn_s_setprio(1);
    #pragma unroll
    for (int ks = 0; ks < 8; ++ks) {
      short8 a = af[ks];
      if (ct < 15)   // prefetch same slot for ct+1; in flight across rest of this ct
        af[ks] = *(const short8*)(Wtp + ((size_t)((ntg + 1) * 8 + ks) * 64 + lane) * 8);
      acc[0] = __builtin_amdgcn_mfma_f32_16x16x32_bf16(a, xf[0][ks], acc[0], 0, 0, 0);
      acc[1] = __builtin_amdgcn_mfma_f32_16x16x32_bf16(a, xf[1][ks], acc[1], 0, 0, 0);
      acc[2] = __builtin_amdgcn_mfma_f32_16x16x32_bf16(a, xf[2][ks], acc[2], 0, 0, 0);
    }
    __builtin_amdgcn_s_setprio(0);
    // shuffle-free: lane's b-half partial goes to channel slot c' = cg + (lgrp&1)*128
    const int cb = (ntg * 2 + (lgrp >> 1) + (lgrp & 1) * 128) * 2;
    #pragma unroll
    for (int et = 0; et < 3; ++et) {
      int e = et * 16 + lane16;
      float part = acc[et][0] * bas[et].x + acc[et][1] * bas[et].y
                 + acc[et][2] * bas[et].z + acc[et][3] * bas[et].w;
      *(ushort*)((char*)Ys + e * 512 + (cb ^ ((e & 7) << 4))) = f2bf(part);
    }
  }

  // --- prefetch ii weight frags BEFORE the barrier (independent of Ys) ---
  short8 iw[2][8];
  #pragma unroll
  for (int dtl = 0; dtl < 2; ++dtl)
    #pragma unroll
    for (int ks = 0; ks < 8; ++ks)
      iw[dtl][ks] = *(const short8*)(iiWtp2 + ((size_t)((wave * 2 + dtl) * 8 + ks) * 64 + lane) * 8);
  float4 iib[2];
  #pragma unroll
  for (int dtl = 0; dtl < 2; ++dtl)
    iib[dtl] = *(const float4*)(ii_b + (wave * 2 + dtl) * 16 + lgrp * 4);

  __syncthreads();

  // --- ii GEMM (swapped, K=256): D[d][e], wave owns d-tiles {wave*2, wave*2+1} ---
  short8 yf[3][8];
  #pragma unroll
  for (int et = 0; et < 3; ++et) {
    int e = et * 16 + lane16;
    #pragma unroll
    for (int ks = 0; ks < 8; ++ks)
      yf[et][ks] = *(const short8*)((const char*)Ys + e * 512 + ((ks * 64 + lgrp * 16) ^ ((e & 7) << 4)));
  }

  f32x4 acc2[3][2];
  #pragma unroll
  for (int et = 0; et < 3; ++et)
    #pragma unroll
    for (int dtl = 0; dtl < 2; ++dtl)
      acc2[et][dtl] = (f32x4){0.f, 0.f, 0.f, 0.f};

  __builtin_amdgcn_s_setprio(1);
  #pragma unroll
  for (int dtl = 0; dtl < 2; ++dtl) {
    #pragma unroll
    for (int ks = 0; ks < 8; ++ks) {
      #pragma unroll
      for (int et = 0; et < 3; ++et)
        acc2[et][dtl] = __builtin_amdgcn_mfma_f32_16x16x32_bf16(iw[dtl][ks], yf[et][ks], acc2[et][dtl], 0, 0, 0);
    }
  }
  __builtin_amdgcn_s_setprio(0);

  // --- tanh, transpose through LDS (reuse Xs as f32 [48][128], swizzled) ---
  float* Tr = (float*)Xs;
  #pragma unroll
  for (int dtl = 0; dtl < 2; ++dtl) {
    int d0 = (wave * 2 + dtl) * 16 + lgrp * 4;
    #pragma unroll
    for (int et = 0; et < 3; ++et) {
      int e = et * 16 + lane16;
      float4 v;
      v.x = fast_tanh(acc2[et][dtl][0] + iib[dtl].x);
      v.y = fast_tanh(acc2[et][dtl][1] + iib[dtl].y);
      v.z = fast_tanh(acc2[et][dtl][2] + iib[dtl].z);
      v.w = fast_tanh(acc2[et][dtl][3] + iib[dtl].w);
      *(float4*)((char*)Tr + e * 512 + ((d0 * 4) ^ ((e & 7) << 4))) = v;
    }
  }
  __syncthreads();

  // --- coalesced atomic scatter: c fixed per thread, e = (tid>>7) + 2p ---
  {
    const int c = tid & 127;
    const int eb = tid >> 7;
    #pragma unroll
    for (int p = 0; p < 24; ++p) {
      int e = eb + p * 2;
      if (FULL || e0 + e < (size_t)E) {
        float v = *(const float*)((const char*)Tr + e * 512 + ((c * 4) ^ ((e & 7) << 4)));
        unsafeAtomicAdd(out + (size_t)idxj_s[e] * 128 + c, v);
      }
    }
  }
}

extern "C" void kernel_launch(void* const* d_in, const int* in_sizes, int n_in,
                              void* d_out, int out_size, void* d_ws, size_t ws_size,
                              hipStream_t stream)
{
  const float* p1    = (const float*)d_in[0];
  const int*   idx_i = (const int*)d_in[1];
  const int*   idx_j = (const int*)d_in[2];
  const float* basis = (const float*)d_in[3];
  const float* pp_w1 = (const float*)d_in[4];
  const float* pp_b1 = (const float*)d_in[5];
  const float* pp_w2 = (const float*)d_in[6];
  const float* pp_b2 = (const float*)d_in[7];
  const float* pi_w  = (const float*)d_in[8];
  const float* pi_b  = (const float*)d_in[9];
  const float* ii_w  = (const float*)d_in[10];
  const float* ii_b  = (const float*)d_in[11];

  const int N = in_sizes[0] / 128;
  const int E = in_sizes[1];

  char* wp = (char*)d_ws;
  ushort* hbf    = (ushort*)wp;  wp += (size_t)N * 128 * 2;
  ushort* Wtp    = (ushort*)wp;  wp += (size_t)262144 * 2;
  ushort* iiWtp2 = (ushort*)wp;  wp += (size_t)32768 * 2;
  ushort* ppW1p  = (ushort*)wp;  wp += (size_t)16384 * 2;
  ushort* ppW2p  = (ushort*)wp;  wp += (size_t)16384 * 2;

  hipMemsetAsync(d_out, 0, (size_t)out_size * sizeof(float), stream);

  prep_weights<<<dim3((262144 + 32768 + 32768) / 256), dim3(256), 0, stream>>>(
      pi_w, ii_w, pp_w1, pp_w2, Wtp, iiWtp2, ppW1p, ppW2p);

  const int ppFull = N / 64;
  pp_mfma_kernel<true><<<dim3(ppFull), dim3(256), 0, stream>>>(
      p1, ppW1p, pp_b1, ppW2p, pp_b2, hbf, N, 0);
  if (N % 64)
    pp_mfma_kernel<false><<<dim3(1), dim3(256), 0, stream>>>(
        p1, ppW1p, pp_b1, ppW2p, pp_b2, hbf, N, ppFull);

  const int edFull = E / 48;
  edge_kernel<true><<<dim3(edFull), dim3(256), 0, stream>>>(
      hbf, idx_i, idx_j, basis, Wtp, pi_b, iiWtp2, ii_b, (float*)d_out, E, 0);
  if (E % 48)
    edge_kernel<false><<<dim3(1), dim3(256), 0, stream>>>(
        hbf, idx_i, idx_j, basis, Wtp, pi_b, iiWtp2, ii_b, (float*)d_out, E, edFull);
}

// Round 14
// 336.964 us; speedup vs baseline: 2.2591x; 2.2591x over previous
//
#include <hip/hip_runtime.h>

typedef __attribute__((ext_vector_type(8))) short short8;
typedef __attribute__((ext_vector_type(4))) float f32x4;

__device__ inline ushort f2bf(float f) {
  union { float f; unsigned u; } v; v.f = f;
  return (ushort)((v.u + 0x7fffu + ((v.u >> 16) & 1u)) >> 16);
}

// tanh via v_exp_f32 + v_rcp_f32: ~8 VALU ops, rel err ~1e-6 (<< bf16 rounding)
__device__ inline float fast_tanh(float x) {
  float ax = __builtin_fabsf(x);
  float u = __builtin_amdgcn_exp2f(-2.8853900817779268f * ax);   // e^{-2|x|}
  float r = (1.0f - u) * __builtin_amdgcn_rcpf(1.0f + u);
  return __builtin_copysignf(r, x);
}

// ---------------- weight prep: pack into per-MFMA-fragment order ----------------
// Wtp [64][8][64][8]: n = nt*16+(lane&15), k = ks*32+(lane>>4)*8+m, pi_w[k*1024+n]
// iiWtp [8][4][64][8]:  d = dt*16+(lane&15), c = ks*32+(lane>>4)*8+m, ii_w[c*128+d]
// ppW1p/ppW2p [8][4][64][8]: c = ct*16+(lane&15), k = ks*32+(lane>>4)*8+m, w[k*128+c]
__global__ __launch_bounds__(256)
void prep_weights(const float* __restrict__ pi_w, const float* __restrict__ ii_w,
                  const float* __restrict__ pp_w1, const float* __restrict__ pp_w2,
                  ushort* __restrict__ Wtp, ushort* __restrict__ iiWtp,
                  ushort* __restrict__ ppW1p, ushort* __restrict__ ppW2p)
{
  int tid = blockIdx.x * 256 + threadIdx.x;
  if (tid < 262144) {
    int m = tid & 7, lane = (tid >> 3) & 63, ks = (tid >> 9) & 7, nt = tid >> 12;
    int k = ks * 32 + (lane >> 4) * 8 + m;
    int n = nt * 16 + (lane & 15);
    Wtp[tid] = f2bf(pi_w[k * 1024 + n]);
  } else {
    int t = tid - 262144;
    int m = t & 7, lane = (t >> 3) & 63, ks = (t >> 9) & 3, ct = (t >> 11) & 7;
    int k = ks * 32 + (lane >> 4) * 8 + m;
    int c = ct * 16 + (lane & 15);
    int which = t >> 14;   // 0: iiWtp, 1: ppW1p, 2: ppW2p
    if (which == 0)      iiWtp[t]           = f2bf(ii_w[k * 128 + c]);
    else if (which == 1) ppW1p[t - 16384]   = f2bf(pp_w1[k * 128 + c]);
    else                 ppW2p[t - 32768]   = f2bf(pp_w2[k * 128 + c]);
  }
}

// ---------------- pp via MFMA: h = tanh(tanh(p1@W1+b1)@W2+b2) -> bf16 ----------------
template <bool FULL>
__global__ __launch_bounds__(256)
void pp_mfma_kernel(const float* __restrict__ p1,
                    const ushort* __restrict__ W1p, const float* __restrict__ b1,
                    const ushort* __restrict__ W2p, const float* __restrict__ b2,
                    ushort* __restrict__ hbf, int N, int blk0)
{
  __shared__ ushort Xs2[64 * 128];   // [n][k] bf16, rows 256B, byte ^= (n&7)<<4
  const int tid = threadIdx.x;
  const int wave = tid >> 6;
  const int lane = tid & 63;
  const int lane16 = lane & 15;
  const int lgrp = lane >> 4;
  const int n0 = (blk0 + (int)blockIdx.x) * 64;

  // --- stage p1 (f32 -> bf16), coalesced ---
  #pragma unroll
  for (int p = 0; p < 8; ++p) {
    int fi = p * 256 + tid;          // float4 index
    int n = fi >> 5;
    int k0 = (fi & 31) * 4;
    int gn = n0 + n;
    if (!FULL) gn = gn < N ? gn : N - 1;
    float4 v = *(const float4*)(p1 + (size_t)gn * 128 + k0);
    ushort4 u;
    u.x = f2bf(v.x); u.y = f2bf(v.y); u.z = f2bf(v.z); u.w = f2bf(v.w);
    *(ushort4*)((char*)Xs2 + n * 256 + ((k0 * 2) ^ ((n & 7) << 4))) = u;
  }
  __syncthreads();

  const ushort* Wp = W1p;
  const float* bp = b1;
  #pragma unroll
  for (int layer = 0; layer < 2; ++layer) {
    short8 xf2[4][4];
    #pragma unroll
    for (int et = 0; et < 4; ++et) {
      int n = et * 16 + lane16;
      #pragma unroll
      for (int ks = 0; ks < 4; ++ks)
        xf2[et][ks] = *(const short8*)((const char*)Xs2 + n * 256 + ((ks * 64 + lgrp * 16) ^ ((n & 7) << 4)));
    }
    ushort4 uo[2][4];
    #pragma unroll
    for (int ct = 0; ct < 2; ++ct) {
      const int ctg = wave * 2 + ct;
      const float4 bb = *(const float4*)(bp + ctg * 16 + lgrp * 4);
      f32x4 acc[4];
      #pragma unroll
      for (int et = 0; et < 4; ++et) acc[et] = (f32x4){bb.x, bb.y, bb.z, bb.w};
      __builtin_amdgcn_s_setprio(1);
      #pragma unroll
      for (int ks = 0; ks < 4; ++ks) {
        short8 a = *(const short8*)(Wp + ((size_t)(ctg * 4 + ks) * 64 + lane) * 8);
        #pragma unroll
        for (int et = 0; et < 4; ++et)
          acc[et] = __builtin_amdgcn_mfma_f32_16x16x32_bf16(a, xf2[et][ks], acc[et], 0, 0, 0);
      }
      __builtin_amdgcn_s_setprio(0);
      #pragma unroll
      for (int et = 0; et < 4; ++et) {
        uo[ct][et].x = f2bf(fast_tanh(acc[et][0]));
        uo[ct][et].y = f2bf(fast_tanh(acc[et][1]));
        uo[ct][et].z = f2bf(fast_tanh(acc[et][2]));
        uo[ct][et].w = f2bf(fast_tanh(acc[et][3]));
      }
    }
    __syncthreads();   // all waves done reading Xs2
    #pragma unroll
    for (int ct = 0; ct < 2; ++ct) {
      int c0 = (wave * 2 + ct) * 16 + lgrp * 4;
      #pragma unroll
      for (int et = 0; et < 4; ++et) {
        int n = et * 16 + lane16;
        *(ushort4*)((char*)Xs2 + n * 256 + ((c0 * 2) ^ ((n & 7) << 4))) = uo[ct][et];
      }
    }
    __syncthreads();
    Wp = W2p; bp = b2;
  }

  // --- coalesced copy-out (16B chunks) ---
  #pragma unroll
  for (int p = 0; p < 4; ++p) {
    int si = p * 256 + tid;
    int n = si >> 4;
    int c0 = (si & 15) * 8;
    int4 v = *(const int4*)((const char*)Xs2 + n * 256 + ((c0 * 2) ^ ((n & 7) << 4)));
    if (FULL || n0 + n < N)
      *(int4*)(hbf + (size_t)(n0 + n) * 128 + c0) = v;
  }
}

// ---------------- fused edge kernel (swapped-operand MFMA, 48 edges/block) ----------------
template <bool FULL>
__global__ __launch_bounds__(256, 3)
void edge_kernel(const ushort* __restrict__ hbf,
                 const int* __restrict__ idx_i, const int* __restrict__ idx_j,
                 const float* __restrict__ basis,
                 const ushort* __restrict__ Wtp,   // packed [64][8][64][8]
                 const float* __restrict__ pi_b,   // [1024]
                 const ushort* __restrict__ iiWtp, // packed [8][4][64][8]
                 const float* __restrict__ ii_b,   // [128]
                 float* __restrict__ out, int E, int blk0)
{
  __shared__ ushort Xs[48 * 256];               // 24 KB; reused as f32 transpose buf
  __shared__ ushort Ys[48 * 128];               // 12 KB
  __shared__ alignas(16) float basis_s[48 * 8];
  __shared__ int idxj_s[48];

  const int tid = threadIdx.x;
  const int wave = tid >> 6;
  const int lane = tid & 63;
  const int lane16 = lane & 15;
  const int lgrp = lane >> 4;
  const size_t e0 = (size_t)(blk0 + (int)blockIdx.x) * 48;
  const size_t elim = (size_t)E - 1;

  // --- stage X (gather 96 rows of 256B, coalesced 16B/lane) ---
  #pragma unroll
  for (int pass = 0; pass < 6; ++pass) {
    int r = pass * 16 + (tid >> 4);
    int l16 = tid & 15;
    int e = r >> 1;
    size_t eg = e0 + e;
    if (!FULL) { if (eg > elim) eg = elim; }
    int node = (r & 1) ? idx_j[eg] : idx_i[eg];
    int4 v = *(const int4*)(hbf + (size_t)node * 128 + l16 * 8);
    int kb = ((r & 1) * 128 + l16 * 8) * 2;
    *(int4*)((char*)Xs + e * 512 + (kb ^ ((e & 7) << 4))) = v;
  }
  if (FULL) {
    basis_s[tid] = basis[e0 * 8 + tid];
    if (tid < 128) basis_s[256 + tid] = basis[e0 * 8 + 256 + tid];
    if (tid < 48) idxj_s[tid] = idx_j[e0 + tid];
  } else {
    size_t blim = (size_t)E * 8 - 1;
    size_t i1 = e0 * 8 + tid;        if (i1 > blim) i1 = blim;
    basis_s[tid] = basis[i1];
    if (tid < 128) {
      size_t i2 = e0 * 8 + 256 + tid; if (i2 > blim) i2 = blim;
      basis_s[256 + tid] = basis[i2];
    }
    if (tid < 48) {
      size_t eg = e0 + tid; if (eg > elim) eg = elim;
      idxj_s[tid] = idx_j[eg];
    }
  }
  __syncthreads();

  // --- hoist X fragments to registers and PIN them (96 regs) ---
  short8 xf[3][8];
  #pragma unroll
  for (int et = 0; et < 3; ++et) {
    int e = et * 16 + lane16;
    #pragma unroll
    for (int ks = 0; ks < 8; ++ks) {
      xf[et][ks] = *(const short8*)((const char*)Xs + e * 512 + ((ks * 64 + lgrp * 16) ^ ((e & 7) << 4)));
      asm volatile("" : "+v"(xf[et][ks]));
    }
  }
  float4 bas[3];
  #pragma unroll
  for (int et = 0; et < 3; ++et) {
    int e = et * 16 + lane16;
    bas[et] = *(const float4*)((const char*)basis_s + e * 32 + (lgrp & 1) * 16);
  }

  // --- pi GEMM + basis fold, rotate-prefetched a-frag stream ---
  short8 af[8];
  #pragma unroll
  for (int ks = 0; ks < 8; ++ks)
    af[ks] = *(const short8*)(Wtp + ((size_t)((wave * 16) * 8 + ks) * 64 + lane) * 8);

  #pragma unroll
  for (int ct = 0; ct < 16; ++ct) {
    const int ntg = wave * 16 + ct;
    const float4 pib = *(const float4*)(pi_b + ntg * 16 + lgrp * 4);
    f32x4 acc[3];
    #pragma unroll
    for (int et = 0; et < 3; ++et)
      acc[et] = (f32x4){pib.x, pib.y, pib.z, pib.w};
    __builtin_amdgcn_s_setprio(1);
    #pragma unroll
    for (int ks = 0; ks < 8; ++ks) {
      short8 a = af[ks];
      if (ct < 15)   // prefetch same slot for ct+1; in flight across rest of this ct
        af[ks] = *(const short8*)(Wtp + ((size_t)((ntg + 1) * 8 + ks) * 64 + lane) * 8);
      acc[0] = __builtin_amdgcn_mfma_f32_16x16x32_bf16(a, xf[0][ks], acc[0], 0, 0, 0);
      acc[1] = __builtin_amdgcn_mfma_f32_16x16x32_bf16(a, xf[1][ks], acc[1], 0, 0, 0);
      acc[2] = __builtin_amdgcn_mfma_f32_16x16x32_bf16(a, xf[2][ks], acc[2], 0, 0, 0);
    }
    __builtin_amdgcn_s_setprio(0);
    const int cg = ntg * 2 + (lgrp >> 1);
    #pragma unroll
    for (int et = 0; et < 3; ++et) {
      int e = et * 16 + lane16;
      float part = acc[et][0] * bas[et].x + acc[et][1] * bas[et].y
                 + acc[et][2] * bas[et].z + acc[et][3] * bas[et].w;
      part += __shfl_xor(part, 16);
      if (!(lgrp & 1))
        *(ushort*)((char*)Ys + e * 256 + ((cg * 2) ^ ((e & 7) << 4))) = f2bf(part);
    }
  }

  // --- prefetch ii weight frags BEFORE the barrier (independent of Ys) ---
  short8 iw[2][4];
  #pragma unroll
  for (int dtl = 0; dtl < 2; ++dtl)
    #pragma unroll
    for (int ks = 0; ks < 4; ++ks)
      iw[dtl][ks] = *(const short8*)(iiWtp + ((size_t)((wave * 2 + dtl) * 4 + ks) * 64 + lane) * 8);
  float4 iib[2];
  #pragma unroll
  for (int dtl = 0; dtl < 2; ++dtl)
    iib[dtl] = *(const float4*)(ii_b + (wave * 2 + dtl) * 16 + lgrp * 4);

  __syncthreads();

  // --- ii GEMM (swapped): D[d][e], wave owns d-tiles {wave*2, wave*2+1} ---
  short8 yf[3][4];
  #pragma unroll
  for (int et = 0; et < 3; ++et) {
    int e = et * 16 + lane16;
    #pragma unroll
    for (int ks = 0; ks < 4; ++ks)
      yf[et][ks] = *(const short8*)((const char*)Ys + e * 256 + ((ks * 64 + lgrp * 16) ^ ((e & 7) << 4)));
  }

  f32x4 acc2[3][2];
  #pragma unroll
  for (int et = 0; et < 3; ++et)
    #pragma unroll
    for (int dtl = 0; dtl < 2; ++dtl)
      acc2[et][dtl] = (f32x4){0.f, 0.f, 0.f, 0.f};

  __builtin_amdgcn_s_setprio(1);
  #pragma unroll
  for (int dtl = 0; dtl < 2; ++dtl) {
    #pragma unroll
    for (int ks = 0; ks < 4; ++ks) {
      #pragma unroll
      for (int et = 0; et < 3; ++et)
        acc2[et][dtl] = __builtin_amdgcn_mfma_f32_16x16x32_bf16(iw[dtl][ks], yf[et][ks], acc2[et][dtl], 0, 0, 0);
    }
  }
  __builtin_amdgcn_s_setprio(0);

  // --- tanh, transpose through LDS (reuse Xs as f32 [48][128], swizzled) ---
  float* Tr = (float*)Xs;
  #pragma unroll
  for (int dtl = 0; dtl < 2; ++dtl) {
    int d0 = (wave * 2 + dtl) * 16 + lgrp * 4;
    #pragma unroll
    for (int et = 0; et < 3; ++et) {
      int e = et * 16 + lane16;
      float4 v;
      v.x = fast_tanh(acc2[et][dtl][0] + iib[dtl].x);
      v.y = fast_tanh(acc2[et][dtl][1] + iib[dtl].y);
      v.z = fast_tanh(acc2[et][dtl][2] + iib[dtl].z);
      v.w = fast_tanh(acc2[et][dtl][3] + iib[dtl].w);
      *(float4*)((char*)Tr + e * 512 + ((d0 * 4) ^ ((e & 7) << 4))) = v;
    }
  }
  __syncthreads();

  // --- coalesced atomic scatter: c fixed per thread, e = (tid>>7) + 2p ---
  {
    const int c = tid & 127;
    const int eb = tid >> 7;
    #pragma unroll
    for (int p = 0; p < 24; ++p) {
      int e = eb + p * 2;
      if (FULL || e0 + e < (size_t)E) {
        float v = *(const float*)((const char*)Tr + e * 512 + ((c * 4) ^ ((e & 7) << 4)));
        unsafeAtomicAdd(out + (size_t)idxj_s[e] * 128 + c, v);
      }
    }
  }
}

extern "C" void kernel_launch(void* const* d_in, const int* in_sizes, int n_in,
                              void* d_out, int out_size, void* d_ws, size_t ws_size,
                              hipStream_t stream)
{
  const float* p1    = (const float*)d_in[0];
  const int*   idx_i = (const int*)d_in[1];
  const int*   idx_j = (const int*)d_in[2];
  const float* basis = (const float*)d_in[3];
  const float* pp_w1 = (const float*)d_in[4];
  const float* pp_b1 = (const float*)d_in[5];
  const float* pp_w2 = (const float*)d_in[6];
  const float* pp_b2 = (const float*)d_in[7];
  const float* pi_w  = (const float*)d_in[8];
  const float* pi_b  = (const float*)d_in[9];
  const float* ii_w  = (const float*)d_in[10];
  const float* ii_b  = (const float*)d_in[11];

  const int N = in_sizes[0] / 128;
  const int E = in_sizes[1];

  char* wp = (char*)d_ws;
  ushort* hbf   = (ushort*)wp;  wp += (size_t)N * 128 * 2;
  ushort* Wtp   = (ushort*)wp;  wp += (size_t)262144 * 2;
  ushort* iiWtp = (ushort*)wp;  wp += (size_t)16384 * 2;
  ushort* ppW1p = (ushort*)wp;  wp += (size_t)16384 * 2;
  ushort* ppW2p = (ushort*)wp;  wp += (size_t)16384 * 2;

  hipMemsetAsync(d_out, 0, (size_t)out_size * sizeof(float), stream);

  prep_weights<<<dim3((262144 + 3 * 16384) / 256), dim3(256), 0, stream>>>(
      pi_w, ii_w, pp_w1, pp_w2, Wtp, iiWtp, ppW1p, ppW2p);

  const int ppFull = N / 64;
  pp_mfma_kernel<true><<<dim3(ppFull), dim3(256), 0, stream>>>(
      p1, ppW1p, pp_b1, ppW2p, pp_b2, hbf, N, 0);
  if (N % 64)
    pp_mfma_kernel<false><<<dim3(1), dim3(256), 0, stream>>>(
        p1, ppW1p, pp_b1, ppW2p, pp_b2, hbf, N, ppFull);

  const int edFull = E / 48;
  edge_kernel<true><<<dim3(edFull), dim3(256), 0, stream>>>(
      hbf, idx_i, idx_j, basis, Wtp, pi_b, iiWtp, ii_b, (float*)d_out, E, 0);
  if (E % 48)
    edge_kernel<false><<<dim3(1), dim3(256), 0, stream>>>(
        hbf, idx_i, idx_j, basis, Wtp, pi_b, iiWtp, ii_b, (float*)d_out, E, edFull);
}

// Round 15
// 331.835 us; speedup vs baseline: 2.2940x; 1.0155x over previous
//
#include <hip/hip_runtime.h>

typedef __attribute__((ext_vector_type(8))) short short8;
typedef __attribute__((ext_vector_type(4))) float f32x4;

__device__ inline ushort f2bf(float f) {
  union { float f; unsigned u; } v; v.f = f;
  return (ushort)((v.u + 0x7fffu + ((v.u >> 16) & 1u)) >> 16);
}

// tanh via v_exp_f32 + v_rcp_f32: ~8 VALU ops, rel err ~1e-6 (<< bf16 rounding)
__device__ inline float fast_tanh(float x) {
  float ax = __builtin_fabsf(x);
  float u = __builtin_amdgcn_exp2f(-2.8853900817779268f * ax);   // e^{-2|x|}
  float r = (1.0f - u) * __builtin_amdgcn_rcpf(1.0f + u);
  return __builtin_copysignf(r, x);
}

// ---------------- weight prep: pack into per-MFMA-fragment order ----------------
// Wtp [64][8][64][8]: n = nt*16+(lane&15), k = ks*32+(lane>>4)*8+m, pi_w[k*1024+n]
// iiWtp [8][4][64][8]:  d = dt*16+(lane&15), c = ks*32+(lane>>4)*8+m, ii_w[c*128+d]
// ppW1p/ppW2p [8][4][64][8]: c = ct*16+(lane&15), k = ks*32+(lane>>4)*8+m, w[k*128+c]
__global__ __launch_bounds__(256)
void prep_weights(const float* __restrict__ pi_w, const float* __restrict__ ii_w,
                  const float* __restrict__ pp_w1, const float* __restrict__ pp_w2,
                  ushort* __restrict__ Wtp, ushort* __restrict__ iiWtp,
                  ushort* __restrict__ ppW1p, ushort* __restrict__ ppW2p)
{
  int tid = blockIdx.x * 256 + threadIdx.x;
  if (tid < 262144) {
    int m = tid & 7, lane = (tid >> 3) & 63, ks = (tid >> 9) & 7, nt = tid >> 12;
    int k = ks * 32 + (lane >> 4) * 8 + m;
    int n = nt * 16 + (lane & 15);
    Wtp[tid] = f2bf(pi_w[k * 1024 + n]);
  } else {
    int t = tid - 262144;
    int m = t & 7, lane = (t >> 3) & 63, ks = (t >> 9) & 3, ct = (t >> 11) & 7;
    int k = ks * 32 + (lane >> 4) * 8 + m;
    int c = ct * 16 + (lane & 15);
    int which = t >> 14;   // 0: iiWtp, 1: ppW1p, 2: ppW2p
    if (which == 0)      iiWtp[t]           = f2bf(ii_w[k * 128 + c]);
    else if (which == 1) ppW1p[t - 16384]   = f2bf(pp_w1[k * 128 + c]);
    else                 ppW2p[t - 32768]   = f2bf(pp_w2[k * 128 + c]);
  }
}

// ---------------- pp via MFMA: h = tanh(tanh(p1@W1+b1)@W2+b2) -> bf16 ----------------
template <bool FULL>
__global__ __launch_bounds__(256)
void pp_mfma_kernel(const float* __restrict__ p1,
                    const ushort* __restrict__ W1p, const float* __restrict__ b1,
                    const ushort* __restrict__ W2p, const float* __restrict__ b2,
                    ushort* __restrict__ hbf, int N, int blk0)
{
  __shared__ ushort Xs2[64 * 128];   // [n][k] bf16, rows 256B, byte ^= (n&7)<<4
  const int tid = threadIdx.x;
  const int wave = tid >> 6;
  const int lane = tid & 63;
  const int lane16 = lane & 15;
  const int lgrp = lane >> 4;
  const int n0 = (blk0 + (int)blockIdx.x) * 64;

  // --- stage p1 (f32 -> bf16), coalesced ---
  #pragma unroll
  for (int p = 0; p < 8; ++p) {
    int fi = p * 256 + tid;          // float4 index
    int n = fi >> 5;
    int k0 = (fi & 31) * 4;
    int gn = n0 + n;
    if (!FULL) gn = gn < N ? gn : N - 1;
    float4 v = *(const float4*)(p1 + (size_t)gn * 128 + k0);
    ushort4 u;
    u.x = f2bf(v.x); u.y = f2bf(v.y); u.z = f2bf(v.z); u.w = f2bf(v.w);
    *(ushort4*)((char*)Xs2 + n * 256 + ((k0 * 2) ^ ((n & 7) << 4))) = u;
  }
  __syncthreads();

  const ushort* Wp = W1p;
  const float* bp = b1;
  #pragma unroll
  for (int layer = 0; layer < 2; ++layer) {
    short8 xf2[4][4];
    #pragma unroll
    for (int et = 0; et < 4; ++et) {
      int n = et * 16 + lane16;
      #pragma unroll
      for (int ks = 0; ks < 4; ++ks)
        xf2[et][ks] = *(const short8*)((const char*)Xs2 + n * 256 + ((ks * 64 + lgrp * 16) ^ ((n & 7) << 4)));
    }
    ushort4 uo[2][4];
    #pragma unroll
    for (int ct = 0; ct < 2; ++ct) {
      const int ctg = wave * 2 + ct;
      const float4 bb = *(const float4*)(bp + ctg * 16 + lgrp * 4);
      f32x4 acc[4];
      #pragma unroll
      for (int et = 0; et < 4; ++et) acc[et] = (f32x4){bb.x, bb.y, bb.z, bb.w};
      __builtin_amdgcn_s_setprio(1);
      #pragma unroll
      for (int ks = 0; ks < 4; ++ks) {
        short8 a = *(const short8*)(Wp + ((size_t)(ctg * 4 + ks) * 64 + lane) * 8);
        #pragma unroll
        for (int et = 0; et < 4; ++et)
          acc[et] = __builtin_amdgcn_mfma_f32_16x16x32_bf16(a, xf2[et][ks], acc[et], 0, 0, 0);
      }
      __builtin_amdgcn_s_setprio(0);
      #pragma unroll
      for (int et = 0; et < 4; ++et) {
        uo[ct][et].x = f2bf(fast_tanh(acc[et][0]));
        uo[ct][et].y = f2bf(fast_tanh(acc[et][1]));
        uo[ct][et].z = f2bf(fast_tanh(acc[et][2]));
        uo[ct][et].w = f2bf(fast_tanh(acc[et][3]));
      }
    }
    __syncthreads();   // all waves done reading Xs2
    #pragma unroll
    for (int ct = 0; ct < 2; ++ct) {
      int c0 = (wave * 2 + ct) * 16 + lgrp * 4;
      #pragma unroll
      for (int et = 0; et < 4; ++et) {
        int n = et * 16 + lane16;
        *(ushort4*)((char*)Xs2 + n * 256 + ((c0 * 2) ^ ((n & 7) << 4))) = uo[ct][et];
      }
    }
    __syncthreads();
    Wp = W2p; bp = b2;
  }

  // --- coalesced copy-out (16B chunks) ---
  #pragma unroll
  for (int p = 0; p < 4; ++p) {
    int si = p * 256 + tid;
    int n = si >> 4;
    int c0 = (si & 15) * 8;
    int4 v = *(const int4*)((const char*)Xs2 + n * 256 + ((c0 * 2) ^ ((n & 7) << 4)));
    if (FULL || n0 + n < N)
      *(int4*)(hbf + (size_t)(n0 + n) * 128 + c0) = v;
  }
}

// ---------------- fused edge kernel (swapped-operand MFMA, 48 edges/block) ----------------
// A/B this round: NO setprio in this kernel (lockstep barrier structure; m190
// evidence says setprio hurts this regime). Everything else identical to R12.
template <bool FULL>
__global__ __launch_bounds__(256, 3)
void edge_kernel(const ushort* __restrict__ hbf,
                 const int* __restrict__ idx_i, const int* __restrict__ idx_j,
                 const float* __restrict__ basis,
                 const ushort* __restrict__ Wtp,   // packed [64][8][64][8]
                 const float* __restrict__ pi_b,   // [1024]
                 const ushort* __restrict__ iiWtp, // packed [8][4][64][8]
                 const float* __restrict__ ii_b,   // [128]
                 float* __restrict__ out, int E, int blk0)
{
  __shared__ ushort Xs[48 * 256];               // 24 KB; reused as f32 transpose buf
  __shared__ ushort Ys[48 * 128];               // 12 KB
  __shared__ alignas(16) float basis_s[48 * 8];
  __shared__ int idxj_s[48];

  const int tid = threadIdx.x;
  const int wave = tid >> 6;
  const int lane = tid & 63;
  const int lane16 = lane & 15;
  const int lgrp = lane >> 4;
  const size_t e0 = (size_t)(blk0 + (int)blockIdx.x) * 48;
  const size_t elim = (size_t)E - 1;

  // --- stage X (gather 96 rows of 256B, coalesced 16B/lane) ---
  #pragma unroll
  for (int pass = 0; pass < 6; ++pass) {
    int r = pass * 16 + (tid >> 4);
    int l16 = tid & 15;
    int e = r >> 1;
    size_t eg = e0 + e;
    if (!FULL) { if (eg > elim) eg = elim; }
    int node = (r & 1) ? idx_j[eg] : idx_i[eg];
    int4 v = *(const int4*)(hbf + (size_t)node * 128 + l16 * 8);
    int kb = ((r & 1) * 128 + l16 * 8) * 2;
    *(int4*)((char*)Xs + e * 512 + (kb ^ ((e & 7) << 4))) = v;
  }
  if (FULL) {
    basis_s[tid] = basis[e0 * 8 + tid];
    if (tid < 128) basis_s[256 + tid] = basis[e0 * 8 + 256 + tid];
    if (tid < 48) idxj_s[tid] = idx_j[e0 + tid];
  } else {
    size_t blim = (size_t)E * 8 - 1;
    size_t i1 = e0 * 8 + tid;        if (i1 > blim) i1 = blim;
    basis_s[tid] = basis[i1];
    if (tid < 128) {
      size_t i2 = e0 * 8 + 256 + tid; if (i2 > blim) i2 = blim;
      basis_s[256 + tid] = basis[i2];
    }
    if (tid < 48) {
      size_t eg = e0 + tid; if (eg > elim) eg = elim;
      idxj_s[tid] = idx_j[eg];
    }
  }
  __syncthreads();

  // --- hoist X fragments to registers and PIN them (96 regs) ---
  short8 xf[3][8];
  #pragma unroll
  for (int et = 0; et < 3; ++et) {
    int e = et * 16 + lane16;
    #pragma unroll
    for (int ks = 0; ks < 8; ++ks) {
      xf[et][ks] = *(const short8*)((const char*)Xs + e * 512 + ((ks * 64 + lgrp * 16) ^ ((e & 7) << 4)));
      asm volatile("" : "+v"(xf[et][ks]));
    }
  }
  float4 bas[3];
  #pragma unroll
  for (int et = 0; et < 3; ++et) {
    int e = et * 16 + lane16;
    bas[et] = *(const float4*)((const char*)basis_s + e * 32 + (lgrp & 1) * 16);
  }

  // --- pi GEMM + basis fold, rotate-prefetched a-frag stream ---
  short8 af[8];
  #pragma unroll
  for (int ks = 0; ks < 8; ++ks)
    af[ks] = *(const short8*)(Wtp + ((size_t)((wave * 16) * 8 + ks) * 64 + lane) * 8);

  #pragma unroll
  for (int ct = 0; ct < 16; ++ct) {
    const int ntg = wave * 16 + ct;
    const float4 pib = *(const float4*)(pi_b + ntg * 16 + lgrp * 4);
    f32x4 acc[3];
    #pragma unroll
    for (int et = 0; et < 3; ++et)
      acc[et] = (f32x4){pib.x, pib.y, pib.z, pib.w};
    #pragma unroll
    for (int ks = 0; ks < 8; ++ks) {
      short8 a = af[ks];
      if (ct < 15)   // prefetch same slot for ct+1; in flight across rest of this ct
        af[ks] = *(const short8*)(Wtp + ((size_t)((ntg + 1) * 8 + ks) * 64 + lane) * 8);
      acc[0] = __builtin_amdgcn_mfma_f32_16x16x32_bf16(a, xf[0][ks], acc[0], 0, 0, 0);
      acc[1] = __builtin_amdgcn_mfma_f32_16x16x32_bf16(a, xf[1][ks], acc[1], 0, 0, 0);
      acc[2] = __builtin_amdgcn_mfma_f32_16x16x32_bf16(a, xf[2][ks], acc[2], 0, 0, 0);
    }
    const int cg = ntg * 2 + (lgrp >> 1);
    #pragma unroll
    for (int et = 0; et < 3; ++et) {
      int e = et * 16 + lane16;
      float part = acc[et][0] * bas[et].x + acc[et][1] * bas[et].y
                 + acc[et][2] * bas[et].z + acc[et][3] * bas[et].w;
      part += __shfl_xor(part, 16);
      if (!(lgrp & 1))
        *(ushort*)((char*)Ys + e * 256 + ((cg * 2) ^ ((e & 7) << 4))) = f2bf(part);
    }
  }

  // --- prefetch ii weight frags BEFORE the barrier (independent of Ys) ---
  short8 iw[2][4];
  #pragma unroll
  for (int dtl = 0; dtl < 2; ++dtl)
    #pragma unroll
    for (int ks = 0; ks < 4; ++ks)
      iw[dtl][ks] = *(const short8*)(iiWtp + ((size_t)((wave * 2 + dtl) * 4 + ks) * 64 + lane) * 8);
  float4 iib[2];
  #pragma unroll
  for (int dtl = 0; dtl < 2; ++dtl)
    iib[dtl] = *(const float4*)(ii_b + (wave * 2 + dtl) * 16 + lgrp * 4);

  __syncthreads();

  // --- ii GEMM (swapped): D[d][e], wave owns d-tiles {wave*2, wave*2+1} ---
  short8 yf[3][4];
  #pragma unroll
  for (int et = 0; et < 3; ++et) {
    int e = et * 16 + lane16;
    #pragma unroll
    for (int ks = 0; ks < 4; ++ks)
      yf[et][ks] = *(const short8*)((const char*)Ys + e * 256 + ((ks * 64 + lgrp * 16) ^ ((e & 7) << 4)));
  }

  f32x4 acc2[3][2];
  #pragma unroll
  for (int et = 0; et < 3; ++et)
    #pragma unroll
    for (int dtl = 0; dtl < 2; ++dtl)
      acc2[et][dtl] = (f32x4){0.f, 0.f, 0.f, 0.f};

  #pragma unroll
  for (int dtl = 0; dtl < 2; ++dtl) {
    #pragma unroll
    for (int ks = 0; ks < 4; ++ks) {
      #pragma unroll
      for (int et = 0; et < 3; ++et)
        acc2[et][dtl] = __builtin_amdgcn_mfma_f32_16x16x32_bf16(iw[dtl][ks], yf[et][ks], acc2[et][dtl], 0, 0, 0);
    }
  }

  // --- tanh, transpose through LDS (reuse Xs as f32 [48][128], swizzled) ---
  float* Tr = (float*)Xs;
  #pragma unroll
  for (int dtl = 0; dtl < 2; ++dtl) {
    int d0 = (wave * 2 + dtl) * 16 + lgrp * 4;
    #pragma unroll
    for (int et = 0; et < 3; ++et) {
      int e = et * 16 + lane16;
      float4 v;
      v.x = fast_tanh(acc2[et][dtl][0] + iib[dtl].x);
      v.y = fast_tanh(acc2[et][dtl][1] + iib[dtl].y);
      v.z = fast_tanh(acc2[et][dtl][2] + iib[dtl].z);
      v.w = fast_tanh(acc2[et][dtl][3] + iib[dtl].w);
      *(float4*)((char*)Tr + e * 512 + ((d0 * 4) ^ ((e & 7) << 4))) = v;
    }
  }
  __syncthreads();

  // --- coalesced atomic scatter: c fixed per thread, e = (tid>>7) + 2p ---
  {
    const int c = tid & 127;
    const int eb = tid >> 7;
    #pragma unroll
    for (int p = 0; p < 24; ++p) {
      int e = eb + p * 2;
      if (FULL || e0 + e < (size_t)E) {
        float v = *(const float*)((const char*)Tr + e * 512 + ((c * 4) ^ ((e & 7) << 4)));
        unsafeAtomicAdd(out + (size_t)idxj_s[e] * 128 + c, v);
      }
    }
  }
}

extern "C" void kernel_launch(void* const* d_in, const int* in_sizes, int n_in,
                              void* d_out, int out_size, void* d_ws, size_t ws_size,
                              hipStream_t stream)
{
  const float* p1    = (const float*)d_in[0];
  const int*   idx_i = (const int*)d_in[1];
  const int*   idx_j = (const int*)d_in[2];
  const float* basis = (const float*)d_in[3];
  const float* pp_w1 = (const float*)d_in[4];
  const float* pp_b1 = (const float*)d_in[5];
  const float* pp_w2 = (const float*)d_in[6];
  const float* pp_b2 = (const float*)d_in[7];
  const float* pi_w  = (const float*)d_in[8];
  const float* pi_b  = (const float*)d_in[9];
  const float* ii_w  = (const float*)d_in[10];
  const float* ii_b  = (const float*)d_in[11];

  const int N = in_sizes[0] / 128;
  const int E = in_sizes[1];

  char* wp = (char*)d_ws;
  ushort* hbf   = (ushort*)wp;  wp += (size_t)N * 128 * 2;
  ushort* Wtp   = (ushort*)wp;  wp += (size_t)262144 * 2;
  ushort* iiWtp = (ushort*)wp;  wp += (size_t)16384 * 2;
  ushort* ppW1p = (ushort*)wp;  wp += (size_t)16384 * 2;
  ushort* ppW2p = (ushort*)wp;  wp += (size_t)16384 * 2;

  hipMemsetAsync(d_out, 0, (size_t)out_size * sizeof(float), stream);

  prep_weights<<<dim3((262144 + 3 * 16384) / 256), dim3(256), 0, stream>>>(
      pi_w, ii_w, pp_w1, pp_w2, Wtp, iiWtp, ppW1p, ppW2p);

  const int ppFull = N / 64;
  pp_mfma_kernel<true><<<dim3(ppFull), dim3(256), 0, stream>>>(
      p1, ppW1p, pp_b1, ppW2p, pp_b2, hbf, N, 0);
  if (N % 64)
    pp_mfma_kernel<false><<<dim3(1), dim3(256), 0, stream>>>(
        p1, ppW1p, pp_b1, ppW2p, pp_b2, hbf, N, ppFull);

  const int edFull = E / 48;
  edge_kernel<true><<<dim3(edFull), dim3(256), 0, stream>>>(
      hbf, idx_i, idx_j, basis, Wtp, pi_b, iiWtp, ii_b, (float*)d_out, E, 0);
  if (E % 48)
    edge_kernel<false><<<dim3(1), dim3(256), 0, stream>>>(
        hbf, idx_i, idx_j, basis, Wtp, pi_b, iiWtp, ii_b, (float*)d_out, E, edFull);
}